// Round 3
// baseline (991.554 us; speedup 1.0000x reference)
//
#include <hip/hip_runtime.h>

#define Bn 16
#define Sn 2048
#define Hn 1024

typedef float floatx4 __attribute__((ext_vector_type(4)));
typedef __bf16 bf16x8 __attribute__((ext_vector_type(8)));
typedef unsigned short ushort8v __attribute__((ext_vector_type(8)));

__device__ __forceinline__ unsigned short f2bf(float f) {
  unsigned u = __builtin_bit_cast(unsigned, f);
  u += 0x7FFFu + ((u >> 16) & 1u);  // RNE
  return (unsigned short)(u >> 16);
}
__device__ __forceinline__ float bf2f(unsigned short h) {
  unsigned u = ((unsigned)h) << 16;
  return __builtin_bit_cast(float, u);
}

__device__ __forceinline__ void async16(const unsigned short* g, unsigned short* l) {
  typedef __attribute__((address_space(1))) const unsigned char gu8;
  typedef __attribute__((address_space(3))) unsigned char lu8;
  __builtin_amdgcn_global_load_lds((gu8*)g, (lu8*)l, 16, 0, 0);
}

// ---- bf16 NT GEMM mainloop: C(128x128) = A(128xK) * B(128xK)^T ----
__device__ __forceinline__ void gemm_bt_main(const unsigned short* __restrict__ Ab,
                                             const unsigned short* __restrict__ Bb,
                                             int lda, int ldb, int K,
                                             unsigned short* As, unsigned short* Bs,
                                             floatx4 acc[4][4]) {
  const int t = threadIdx.x;
  const int l = t & 63;
  const int w = t >> 6;
  const int wm = w >> 1, wn = w & 1;
  const int sr = t >> 2;
  const int sc = (t & 3) << 3;
#pragma unroll
  for (int i = 0; i < 4; ++i)
#pragma unroll
    for (int j = 0; j < 4; ++j) acc[i][j] = (floatx4){0.f, 0.f, 0.f, 0.f};

  const int am = wm * 64 + (l & 15);
  const int bn = wn * 64 + (l & 15);
  const int kq = (l >> 4) << 3;

  for (int k0 = 0; k0 < K; k0 += 32) {
    async16(Ab + (size_t)sr * lda + k0 + sc, As + t * 8);
    async16(Ab + (size_t)(sr + 64) * lda + k0 + sc, As + 2048 + t * 8);
    async16(Bb + (size_t)sr * ldb + k0 + sc, Bs + t * 8);
    async16(Bb + (size_t)(sr + 64) * ldb + k0 + sc, Bs + 2048 + t * 8);
    __syncthreads();
    bf16x8 af[4], bfr[4];
#pragma unroll
    for (int rt = 0; rt < 4; ++rt)
      af[rt] = *(const bf16x8*)(const void*)(As + (am + rt * 16) * 32 + kq);
#pragma unroll
    for (int ct = 0; ct < 4; ++ct)
      bfr[ct] = *(const bf16x8*)(const void*)(Bs + (bn + ct * 16) * 32 + kq);
#pragma unroll
    for (int rt = 0; rt < 4; ++rt)
#pragma unroll
      for (int ct = 0; ct < 4; ++ct)
        acc[rt][ct] = __builtin_amdgcn_mfma_f32_16x16x32_bf16(af[rt], bfr[ct], acc[rt][ct], 0, 0, 0);
    __syncthreads();
  }
}

// ---- K0: fp32 -> bf16 conversion of X and the three W matrices ----
__global__ __launch_bounds__(256) void k_cvt(const float* __restrict__ X,
                                             const float* __restrict__ Wq,
                                             const float* __restrict__ Wk,
                                             const float* __restrict__ Wv,
                                             unsigned short* __restrict__ Xb,
                                             unsigned short* __restrict__ Wb) {
  const size_t NX = (size_t)Bn * Sn * Hn;
  const size_t NW = (size_t)Hn * Hn;
  size_t i = ((size_t)blockIdx.x * 256 + threadIdx.x) * 8;
  const float* src;
  unsigned short* dst;
  if (i < NX) {
    src = X + i;
    dst = Xb + i;
  } else {
    size_t j = i - NX;
    int wsel = (int)(j >> 20);
    size_t o = j & (NW - 1);
    src = (wsel == 0 ? Wq : wsel == 1 ? Wk : Wv) + o;
    dst = Wb + j;
  }
  float4 a = *(const float4*)src;
  float4 b = *(const float4*)(src + 4);
  ushort8v o8;
  o8[0] = f2bf(a.x); o8[1] = f2bf(a.y); o8[2] = f2bf(a.z); o8[3] = f2bf(a.w);
  o8[4] = f2bf(b.x); o8[5] = f2bf(b.y); o8[6] = f2bf(b.z); o8[7] = f2bf(b.w);
  *(ushort8v*)(void*)(dst) = o8;
}

// ---- K1: fused QKV projection GEMM, XCD-swizzled 1D grid of 6144 ----
// bid -> xcd=bid&7, lid=bid>>3; seln=lid%24 (fast), mloc=lid/24; m_tile=xcd*32+mloc
// sel 0 (Q): out scaled by 1/32.  sel 2 (V): transposed store Vt[b][h][s].
__global__ __launch_bounds__(256) void k_projall(const unsigned short* __restrict__ Xb,
                                                 const unsigned short* __restrict__ Wb,
                                                 const float* __restrict__ bq,
                                                 const float* __restrict__ bk,
                                                 const float* __restrict__ bv,
                                                 unsigned short* __restrict__ Qb,
                                                 unsigned short* __restrict__ Kb,
                                                 unsigned short* __restrict__ Vt) {
  __shared__ unsigned short lds[16384];  // union: staging 2x4096 | transpose 128x128 swizzled
  unsigned short* As = lds;
  unsigned short* Bs = lds + 4096;
  const int bid = blockIdx.x;
  const int xcd = bid & 7, lid = bid >> 3;
  const int seln = lid % 24, mloc = lid / 24;
  const int sel = seln >> 3;
  const int n0 = (seln & 7) * 128;
  const int m0 = (xcd * 32 + mloc) * 128;
  const unsigned short* Ab = Xb + (size_t)m0 * Hn;
  const unsigned short* Bb = Wb + (size_t)sel * Hn * Hn + (size_t)n0 * Hn;
  floatx4 acc[4][4];
  gemm_bt_main(Ab, Bb, Hn, Hn, Hn, As, Bs, acc);

  const int t = threadIdx.x, l = t & 63, w = t >> 6;
  const int wm = w >> 1, wn = w & 1;
  const int quad = l >> 4;
  const float* bias = sel == 0 ? bq : sel == 1 ? bk : bv;
  const float oscale = sel == 0 ? 0.03125f : 1.0f;  // fold 1/32 into Q (exact)

  if (sel < 2) {
    unsigned short* Out = sel == 0 ? Qb : Kb;
#pragma unroll
    for (int ct = 0; ct < 4; ++ct) {
      const int col = n0 + wn * 64 + ct * 16 + (l & 15);
      const float bb = bias[col];
#pragma unroll
      for (int rt = 0; rt < 4; ++rt) {
        const int row = m0 + wm * 64 + rt * 16 + (quad << 2);
#pragma unroll
        for (int r = 0; r < 4; ++r)
          Out[(size_t)(row + r) * Hn + col] = f2bf((acc[rt][ct][r] + bb) * oscale);
      }
    }
  } else {
    __syncthreads();  // staging LDS now reusable as transpose buffer
    // swizzled layout: elt addr = nl*128 + ((g ^ (nl&15))*8 + off), g=ml>>3, off=ml&7
#pragma unroll
    for (int ct = 0; ct < 4; ++ct) {
      const int nl = wn * 64 + ct * 16 + (l & 15);
      const float bb = bias[n0 + nl];
#pragma unroll
      for (int rt = 0; rt < 4; ++rt) {
        const int ml = wm * 64 + rt * 16 + (quad << 2);
        const int ga = ((ml >> 3) ^ (nl & 15)) * 8 + (ml & 7);
        ushort4 pk = make_ushort4(f2bf(acc[rt][ct][0] + bb), f2bf(acc[rt][ct][1] + bb),
                                  f2bf(acc[rt][ct][2] + bb), f2bf(acc[rt][ct][3] + bb));
        *(ushort4*)(void*)(lds + nl * 128 + ga) = pk;  // ds_write_b64
      }
    }
    __syncthreads();
    const int bidx = m0 >> 11;
    const int mrow = m0 & (Sn - 1);
    unsigned short* Vp = Vt + (size_t)bidx * Hn * Sn + mrow;
#pragma unroll
    for (int j = 0; j < 8; ++j) {
      const int e = (j * 256 + t) * 8;
      const int nl = e >> 7, mlg = (e & 127) >> 3;
      bf16x8 v = *(const bf16x8*)(const void*)(lds + nl * 128 + (mlg ^ (nl & 15)) * 8);
      *(bf16x8*)(void*)(Vp + (size_t)(n0 + nl) * Sn + mlg * 8) = v;
    }
  }
}

// ---- K2: Sc[b][q][k] = mask_k ? exp(Q'_b @ K_b^T) : 0  (Q pre-scaled by 1/32)
//      + fp32 row-sum partials atomically accumulated into Lsum[b][q].
// XCD-swizzled 1D grid 4096: xcd=bid&7, lid=bid>>3; b=xcd*2+(lid>>8); n fast.
__global__ __launch_bounds__(256) void k_scores(const unsigned short* __restrict__ Q,
                                                const unsigned short* __restrict__ Kmat,
                                                const int* __restrict__ mask,
                                                unsigned short* __restrict__ Sc,
                                                float* __restrict__ Lsum) {
  __shared__ unsigned short As[128 * 32], Bs[128 * 32];
  const int bid = blockIdx.x;
  const int xcd = bid & 7, lid = bid >> 3;
  const int b = xcd * 2 + (lid >> 8);
  const int tl = lid & 255;
  const int n0 = (tl & 15) * 128, m0 = (tl >> 4) * 128;
  const unsigned short* Ab = Q + (size_t)b * Sn * Hn + (size_t)m0 * Hn;
  const unsigned short* Bb = Kmat + (size_t)b * Sn * Hn + (size_t)n0 * Hn;
  floatx4 acc[4][4];
  gemm_bt_main(Ab, Bb, Hn, Hn, Hn, As, Bs, acc);

  const int t = threadIdx.x, l = t & 63, w = t >> 6;
  const int wm = w >> 1, wn = w & 1;
  const int quad = l >> 4;
  unsigned short* C = Sc + (size_t)b * Sn * Sn;
  const int* mrow = mask + b * Sn;
  float rs[4][4];
#pragma unroll
  for (int rt = 0; rt < 4; ++rt)
#pragma unroll
    for (int r = 0; r < 4; ++r) rs[rt][r] = 0.f;
#pragma unroll
  for (int ct = 0; ct < 4; ++ct) {
    const int col = n0 + wn * 64 + ct * 16 + (l & 15);
    const int mk = mrow[col];
#pragma unroll
    for (int rt = 0; rt < 4; ++rt) {
      const int row = m0 + wm * 64 + rt * 16 + (quad << 2);
#pragma unroll
      for (int r = 0; r < 4; ++r) {
        const float e = mk != 0 ? __expf(acc[rt][ct][r]) : 0.f;  // |s|<~10, no max needed
        C[(size_t)(row + r) * Sn + col] = f2bf(e);
        rs[rt][r] += e;
      }
    }
  }
  // reduce partial row-sums across the 16 col-lanes of each quad
#pragma unroll
  for (int rt = 0; rt < 4; ++rt)
#pragma unroll
    for (int r = 0; r < 4; ++r) {
      float v = rs[rt][r];
      v += __shfl_xor(v, 1);
      v += __shfl_xor(v, 2);
      v += __shfl_xor(v, 4);
      v += __shfl_xor(v, 8);
      rs[rt][r] = v;
    }
  if ((l & 15) == 0) {
#pragma unroll
    for (int rt = 0; rt < 4; ++rt)
#pragma unroll
      for (int r = 0; r < 4; ++r)
        atomicAdd(&Lsum[b * Sn + m0 + wm * 64 + rt * 16 + (quad << 2) + r], rs[rt][r]);
  }
}

// ---- K3: Out[b][q][h] = (Sc_b @ Vt_b^T) * (qmask ? 1/Lsum : 0), fp32 out ----
// XCD-swizzled 1D grid 2048: xcd=bid&7, lid=bid>>3; b=xcd*2+(lid>>7); n fast.
__global__ __launch_bounds__(256) void k_out(const unsigned short* __restrict__ Wt,
                                             const unsigned short* __restrict__ Vt,
                                             const int* __restrict__ mask,
                                             const float* __restrict__ Lsum,
                                             float* __restrict__ Out) {
  __shared__ unsigned short As[128 * 32], Bs[128 * 32];
  const int bid = blockIdx.x;
  const int xcd = bid & 7, lid = bid >> 3;
  const int b = xcd * 2 + (lid >> 7);
  const int tl = lid & 127;
  const int n0 = (tl & 7) * 128, m0 = (tl >> 3) * 128;
  const unsigned short* Ab = Wt + (size_t)b * Sn * Sn + (size_t)m0 * Sn;
  const unsigned short* Bb = Vt + (size_t)b * Hn * Sn + (size_t)n0 * Sn;
  floatx4 acc[4][4];
  gemm_bt_main(Ab, Bb, Sn, Sn, Sn, As, Bs, acc);

  const int t = threadIdx.x, l = t & 63, w = t >> 6;
  const int wm = w >> 1, wn = w & 1;
  const int quad = l >> 4;
  float* C = Out + (size_t)b * Sn * Hn;
  const int* mrow = mask + b * Sn;
#pragma unroll
  for (int rt = 0; rt < 4; ++rt) {
    const int row = m0 + wm * 64 + rt * 16 + (quad << 2);
    float inv[4];
#pragma unroll
    for (int r = 0; r < 4; ++r)
      inv[r] = mrow[row + r] != 0 ? 1.0f / Lsum[b * Sn + row + r] : 0.f;
#pragma unroll
    for (int ct = 0; ct < 4; ++ct) {
      const int col = n0 + wn * 64 + ct * 16 + (l & 15);
#pragma unroll
      for (int r = 0; r < 4; ++r)
        C[(size_t)(row + r) * Hn + col] = acc[rt][ct][r] * inv[r];
    }
  }
}

extern "C" void kernel_launch(void* const* d_in, const int* in_sizes, int n_in,
                              void* d_out, int out_size, void* d_ws, size_t ws_size,
                              hipStream_t stream) {
  const float* X = (const float*)d_in[0];
  const int* mask = (const int*)d_in[1];
  const float* Wq = (const float*)d_in[2];
  const float* bq = (const float*)d_in[3];
  const float* Wk = (const float*)d_in[4];
  const float* bk = (const float*)d_in[5];
  const float* Wv = (const float*)d_in[6];
  const float* bv = (const float*)d_in[7];
  float* Out = (float*)d_out;

  const size_t NE = (size_t)Bn * Sn * Hn;      // 33,554,432
  const size_t NW = (size_t)Hn * Hn;
  unsigned short* Qb = (unsigned short*)d_ws;  // 64 MiB
  unsigned short* Kb = Qb + NE;                // 64 MiB
  unsigned short* Vt = Kb + NE;                // 64 MiB, layout [b][h][s]
  unsigned short* Sc = Vt + NE;                // 128 MiB, layout [b][q][k]
  unsigned short* Xb = Sc + (size_t)Bn * Sn * Sn;  // 64 MiB
  unsigned short* Wb = Xb + NE;                // 6 MiB, [3][Hn][Hn]
  float* Lsum = (float*)Xb;  // 128 KiB, aliases Xb (dead after k_projall)

  dim3 blk(256, 1, 1);
  const int cvt_blocks = (int)((NE + 3 * NW) / 8 / 256);
  k_cvt<<<dim3(cvt_blocks, 1, 1), blk, 0, stream>>>(X, Wq, Wk, Wv, Xb, Wb);
  k_projall<<<dim3(6144, 1, 1), blk, 0, stream>>>(Xb, Wb, bq, bk, bv, Qb, Kb, Vt);
  hipMemsetAsync(Lsum, 0, (size_t)Bn * Sn * sizeof(float), stream);
  k_scores<<<dim3(4096, 1, 1), blk, 0, stream>>>(Qb, Kb, mask, Sc, Lsum);
  k_out<<<dim3(2048, 1, 1), blk, 0, stream>>>(Sc, Vt, mask, Lsum, Out);
}

// Round 4
// 923.120 us; speedup vs baseline: 1.0741x; 1.0741x over previous
//
#include <hip/hip_runtime.h>

#define Bn 16
#define Sn 2048
#define Hn 1024

typedef float floatx4 __attribute__((ext_vector_type(4)));
typedef __bf16 bf16x8 __attribute__((ext_vector_type(8)));
typedef unsigned short ushort8v __attribute__((ext_vector_type(8)));

__device__ __forceinline__ unsigned short f2bf(float f) {
  unsigned u = __builtin_bit_cast(unsigned, f);
  u += 0x7FFFu + ((u >> 16) & 1u);  // RNE
  return (unsigned short)(u >> 16);
}

__device__ __forceinline__ void async16(const unsigned short* g, unsigned short* l) {
  typedef __attribute__((address_space(1))) const unsigned char gu8;
  typedef __attribute__((address_space(3))) unsigned char lu8;
  __builtin_amdgcn_global_load_lds((gu8*)g, (lu8*)l, 16, 0, 0);
}

// ---- bf16 NT GEMM mainloop: C(128x128) = A(128xK) * B(128xK)^T ----
__device__ __forceinline__ void gemm_bt_main(const unsigned short* __restrict__ Ab,
                                             const unsigned short* __restrict__ Bb,
                                             int lda, int ldb, int K,
                                             unsigned short* As, unsigned short* Bs,
                                             floatx4 acc[4][4]) {
  const int t = threadIdx.x;
  const int l = t & 63;
  const int w = t >> 6;
  const int wm = w >> 1, wn = w & 1;
  const int sr = t >> 2;
  const int sc = (t & 3) << 3;
#pragma unroll
  for (int i = 0; i < 4; ++i)
#pragma unroll
    for (int j = 0; j < 4; ++j) acc[i][j] = (floatx4){0.f, 0.f, 0.f, 0.f};

  const int am = wm * 64 + (l & 15);
  const int bn = wn * 64 + (l & 15);
  const int kq = (l >> 4) << 3;

  for (int k0 = 0; k0 < K; k0 += 32) {
    async16(Ab + (size_t)sr * lda + k0 + sc, As + t * 8);
    async16(Ab + (size_t)(sr + 64) * lda + k0 + sc, As + 2048 + t * 8);
    async16(Bb + (size_t)sr * ldb + k0 + sc, Bs + t * 8);
    async16(Bb + (size_t)(sr + 64) * ldb + k0 + sc, Bs + 2048 + t * 8);
    __syncthreads();
    bf16x8 af[4], bfr[4];
#pragma unroll
    for (int rt = 0; rt < 4; ++rt)
      af[rt] = *(const bf16x8*)(const void*)(As + (am + rt * 16) * 32 + kq);
#pragma unroll
    for (int ct = 0; ct < 4; ++ct)
      bfr[ct] = *(const bf16x8*)(const void*)(Bs + (bn + ct * 16) * 32 + kq);
#pragma unroll
    for (int rt = 0; rt < 4; ++rt)
#pragma unroll
      for (int ct = 0; ct < 4; ++ct)
        acc[rt][ct] = __builtin_amdgcn_mfma_f32_16x16x32_bf16(af[rt], bfr[ct], acc[rt][ct], 0, 0, 0);
    __syncthreads();
  }
}

// ---- K0: fp32 -> bf16 conversion of X and the three W matrices ----
// Sources are read-once: nontemporal loads keep L3 free for the Xb/Wb writes
// (Xb is re-read 24x by k_projall and must stay L3-resident).
__global__ __launch_bounds__(256) void k_cvt(const float* __restrict__ X,
                                             const float* __restrict__ Wq,
                                             const float* __restrict__ Wk,
                                             const float* __restrict__ Wv,
                                             unsigned short* __restrict__ Xb,
                                             unsigned short* __restrict__ Wb) {
  const size_t NX = (size_t)Bn * Sn * Hn;
  const size_t NW = (size_t)Hn * Hn;
  size_t i = ((size_t)blockIdx.x * 256 + threadIdx.x) * 8;
  const float* src;
  unsigned short* dst;
  if (i < NX) {
    src = X + i;
    dst = Xb + i;
  } else {
    size_t j = i - NX;
    int wsel = (int)(j >> 20);
    size_t o = j & (NW - 1);
    src = (wsel == 0 ? Wq : wsel == 1 ? Wk : Wv) + o;
    dst = Wb + j;
  }
  floatx4 a = __builtin_nontemporal_load((const floatx4*)src);
  floatx4 b = __builtin_nontemporal_load((const floatx4*)(src + 4));
  ushort8v o8;
  o8[0] = f2bf(a[0]); o8[1] = f2bf(a[1]); o8[2] = f2bf(a[2]); o8[3] = f2bf(a[3]);
  o8[4] = f2bf(b[0]); o8[5] = f2bf(b[1]); o8[6] = f2bf(b[2]); o8[7] = f2bf(b[3]);
  *(ushort8v*)(void*)(dst) = o8;
}

// ---- K1: fused QKV projection GEMM (R2-proven dispatch order) ----
// blockIdx.x: 0..23 -> sel = x>>3 (0=Q,1=K,2=V), n0 = (x&7)*128; blockIdx.y: m-tile.
// sel 0 (Q): out scaled by 1/32 (exact pow2). sel 2 (V): transposed store Vt[b][h][s], nt.
__global__ __launch_bounds__(256) void k_projall(const unsigned short* __restrict__ Xb,
                                                 const unsigned short* __restrict__ Wb,
                                                 const float* __restrict__ bq,
                                                 const float* __restrict__ bk,
                                                 const float* __restrict__ bv,
                                                 unsigned short* __restrict__ Qb,
                                                 unsigned short* __restrict__ Kb,
                                                 unsigned short* __restrict__ Vt) {
  __shared__ unsigned short lds[16384];  // union: staging 2x4096 | transpose 128x128 swizzled
  unsigned short* As = lds;
  unsigned short* Bs = lds + 4096;
  const int sel = blockIdx.x >> 3;
  const int n0 = (blockIdx.x & 7) * 128;
  const int m0 = blockIdx.y * 128;
  const unsigned short* Ab = Xb + (size_t)m0 * Hn;
  const unsigned short* Bb = Wb + (size_t)sel * Hn * Hn + (size_t)n0 * Hn;
  floatx4 acc[4][4];
  gemm_bt_main(Ab, Bb, Hn, Hn, Hn, As, Bs, acc);

  const int t = threadIdx.x, l = t & 63, w = t >> 6;
  const int wm = w >> 1, wn = w & 1;
  const int quad = l >> 4;
  const float* bias = sel == 0 ? bq : sel == 1 ? bk : bv;
  const float oscale = sel == 0 ? 0.03125f : 1.0f;

  if (sel < 2) {
    unsigned short* Out = sel == 0 ? Qb : Kb;
#pragma unroll
    for (int ct = 0; ct < 4; ++ct) {
      const int col = n0 + wn * 64 + ct * 16 + (l & 15);
      const float bb = bias[col];
#pragma unroll
      for (int rt = 0; rt < 4; ++rt) {
        const int row = m0 + wm * 64 + rt * 16 + (quad << 2);
#pragma unroll
        for (int r = 0; r < 4; ++r)
          Out[(size_t)(row + r) * Hn + col] = f2bf((acc[rt][ct][r] + bb) * oscale);
      }
    }
  } else {
    __syncthreads();  // staging LDS now reusable as transpose buffer
    // swizzled layout: elt addr = nl*128 + ((g ^ (nl&15))*8 + off), g=ml>>3, off=ml&7
#pragma unroll
    for (int ct = 0; ct < 4; ++ct) {
      const int nl = wn * 64 + ct * 16 + (l & 15);
      const float bb = bias[n0 + nl];
#pragma unroll
      for (int rt = 0; rt < 4; ++rt) {
        const int ml = wm * 64 + rt * 16 + (quad << 2);
        const int ga = ((ml >> 3) ^ (nl & 15)) * 8 + (ml & 7);
        ushort4 pk = make_ushort4(f2bf(acc[rt][ct][0] + bb), f2bf(acc[rt][ct][1] + bb),
                                  f2bf(acc[rt][ct][2] + bb), f2bf(acc[rt][ct][3] + bb));
        *(ushort4*)(void*)(lds + nl * 128 + ga) = pk;  // ds_write_b64
      }
    }
    __syncthreads();
    const int bidx = m0 >> 11;
    const int mrow = m0 & (Sn - 1);
    unsigned short* Vp = Vt + (size_t)bidx * Hn * Sn + mrow;
#pragma unroll
    for (int j = 0; j < 8; ++j) {
      const int e = (j * 256 + t) * 8;
      const int nl = e >> 7, mlg = (e & 127) >> 3;
      bf16x8 v = *(const bf16x8*)(const void*)(lds + nl * 128 + (mlg ^ (nl & 15)) * 8);
      __builtin_nontemporal_store(v, (bf16x8*)(void*)(Vp + (size_t)(n0 + nl) * Sn + mlg * 8));
    }
  }
}

// ---- K2: Sc[b][q][k] = mask_k ? exp(Q'_b @ K_b^T) : 0  (Q pre-scaled by 1/32)
//      + fp32 row-sum partials atomically accumulated into Lsum[b][q].
__global__ __launch_bounds__(256) void k_scores(const unsigned short* __restrict__ Q,
                                                const unsigned short* __restrict__ Kmat,
                                                const int* __restrict__ mask,
                                                unsigned short* __restrict__ Sc,
                                                float* __restrict__ Lsum) {
  __shared__ unsigned short As[128 * 32], Bs[128 * 32];
  const int b = blockIdx.z;
  const int n0 = blockIdx.x * 128, m0 = blockIdx.y * 128;
  const unsigned short* Ab = Q + (size_t)b * Sn * Hn + (size_t)m0 * Hn;
  const unsigned short* Bb = Kmat + (size_t)b * Sn * Hn + (size_t)n0 * Hn;
  floatx4 acc[4][4];
  gemm_bt_main(Ab, Bb, Hn, Hn, Hn, As, Bs, acc);

  const int t = threadIdx.x, l = t & 63, w = t >> 6;
  const int wm = w >> 1, wn = w & 1;
  const int quad = l >> 4;
  unsigned short* C = Sc + (size_t)b * Sn * Sn;
  const int* mrow = mask + b * Sn;
  float rs[4][4];
#pragma unroll
  for (int rt = 0; rt < 4; ++rt)
#pragma unroll
    for (int r = 0; r < 4; ++r) rs[rt][r] = 0.f;
#pragma unroll
  for (int ct = 0; ct < 4; ++ct) {
    const int col = n0 + wn * 64 + ct * 16 + (l & 15);
    const int mk = mrow[col];
#pragma unroll
    for (int rt = 0; rt < 4; ++rt) {
      const int row = m0 + wm * 64 + rt * 16 + (quad << 2);
#pragma unroll
      for (int r = 0; r < 4; ++r) {
        const float e = mk != 0 ? __expf(acc[rt][ct][r]) : 0.f;  // |s|<~10, no max needed
        C[(size_t)(row + r) * Sn + col] = f2bf(e);
        rs[rt][r] += e;
      }
    }
  }
#pragma unroll
  for (int rt = 0; rt < 4; ++rt)
#pragma unroll
    for (int r = 0; r < 4; ++r) {
      float v = rs[rt][r];
      v += __shfl_xor(v, 1);
      v += __shfl_xor(v, 2);
      v += __shfl_xor(v, 4);
      v += __shfl_xor(v, 8);
      rs[rt][r] = v;
    }
  if ((l & 15) == 0) {
#pragma unroll
    for (int rt = 0; rt < 4; ++rt)
#pragma unroll
      for (int r = 0; r < 4; ++r)
        atomicAdd(&Lsum[b * Sn + m0 + wm * 64 + rt * 16 + (quad << 2) + r], rs[rt][r]);
  }
}

// ---- K3: Out[b][q][h] = (Sc_b @ Vt_b^T) * (qmask ? 1/Lsum : 0), fp32 nt out ----
__global__ __launch_bounds__(256) void k_out(const unsigned short* __restrict__ Wt,
                                             const unsigned short* __restrict__ Vt,
                                             const int* __restrict__ mask,
                                             const float* __restrict__ Lsum,
                                             float* __restrict__ Out) {
  __shared__ unsigned short As[128 * 32], Bs[128 * 32];
  const int b = blockIdx.z;
  const int n0 = blockIdx.x * 128, m0 = blockIdx.y * 128;
  const unsigned short* Ab = Wt + (size_t)b * Sn * Sn + (size_t)m0 * Sn;
  const unsigned short* Bb = Vt + (size_t)b * Hn * Sn + (size_t)n0 * Sn;
  floatx4 acc[4][4];
  gemm_bt_main(Ab, Bb, Sn, Sn, Sn, As, Bs, acc);

  const int t = threadIdx.x, l = t & 63, w = t >> 6;
  const int wm = w >> 1, wn = w & 1;
  const int quad = l >> 4;
  float* C = Out + (size_t)b * Sn * Hn;
  const int* mrow = mask + b * Sn;
#pragma unroll
  for (int rt = 0; rt < 4; ++rt) {
    const int row = m0 + wm * 64 + rt * 16 + (quad << 2);
    float inv[4];
#pragma unroll
    for (int r = 0; r < 4; ++r)
      inv[r] = mrow[row + r] != 0 ? 1.0f / Lsum[b * Sn + row + r] : 0.f;
#pragma unroll
    for (int ct = 0; ct < 4; ++ct) {
      const int col = n0 + wn * 64 + ct * 16 + (l & 15);
#pragma unroll
      for (int r = 0; r < 4; ++r)
        __builtin_nontemporal_store(acc[rt][ct][r] * inv[r],
                                    &C[(size_t)(row + r) * Hn + col]);
    }
  }
}

extern "C" void kernel_launch(void* const* d_in, const int* in_sizes, int n_in,
                              void* d_out, int out_size, void* d_ws, size_t ws_size,
                              hipStream_t stream) {
  const float* X = (const float*)d_in[0];
  const int* mask = (const int*)d_in[1];
  const float* Wq = (const float*)d_in[2];
  const float* bq = (const float*)d_in[3];
  const float* Wk = (const float*)d_in[4];
  const float* bk = (const float*)d_in[5];
  const float* Wv = (const float*)d_in[6];
  const float* bv = (const float*)d_in[7];
  float* Out = (float*)d_out;

  const size_t NE = (size_t)Bn * Sn * Hn;      // 33,554,432
  const size_t NW = (size_t)Hn * Hn;
  unsigned short* Qb = (unsigned short*)d_ws;  // 64 MiB
  unsigned short* Kb = Qb + NE;                // 64 MiB
  unsigned short* Vt = Kb + NE;                // 64 MiB, layout [b][h][s]
  unsigned short* Sc = Vt + NE;                // 128 MiB, layout [b][q][k]
  unsigned short* Xb = Sc + (size_t)Bn * Sn * Sn;  // 64 MiB
  unsigned short* Wb = Xb + NE;                // 6 MiB, [3][Hn][Hn]
  float* Lsum = (float*)Wb;                    // 128 KiB, aliases Wb (dead after projall)

  dim3 blk(256, 1, 1);
  const int cvt_blocks = (int)((NE + 3 * NW) / 8 / 256);
  k_cvt<<<dim3(cvt_blocks, 1, 1), blk, 0, stream>>>(X, Wq, Wk, Wv, Xb, Wb);
  k_projall<<<dim3(24, (Bn * Sn) / 128, 1), blk, 0, stream>>>(Xb, Wb, bq, bk, bv, Qb, Kb, Vt);
  hipMemsetAsync(Lsum, 0, (size_t)Bn * Sn * sizeof(float), stream);
  k_scores<<<dim3(Sn / 128, Sn / 128, Bn), blk, 0, stream>>>(Qb, Kb, mask, Sc, Lsum);
  k_out<<<dim3(Hn / 128, Sn / 128, Bn), blk, 0, stream>>>(Sc, Vt, mask, Lsum, Out);
}

// Round 5
// 914.753 us; speedup vs baseline: 1.0840x; 1.0091x over previous
//
#include <hip/hip_runtime.h>

#define Bn 16
#define Sn 2048
#define Hn 1024

typedef float floatx4 __attribute__((ext_vector_type(4)));
typedef float floatx16 __attribute__((ext_vector_type(16)));
typedef __bf16 bf16x8 __attribute__((ext_vector_type(8)));
typedef unsigned short ushort8v __attribute__((ext_vector_type(8)));

__device__ __forceinline__ unsigned short f2bf(float f) {
  unsigned u = __builtin_bit_cast(unsigned, f);
  u += 0x7FFFu + ((u >> 16) & 1u);  // RNE
  return (unsigned short)(u >> 16);
}

__device__ __forceinline__ void async16(const unsigned short* g, unsigned short* l) {
  typedef __attribute__((address_space(1))) const unsigned char gu8;
  typedef __attribute__((address_space(3))) unsigned char lu8;
  __builtin_amdgcn_global_load_lds((gu8*)g, (lu8*)l, 16, 0, 0);
}

// ---- bf16 NT GEMM mainloop, 32x32x16 MFMA core ----
// C(128x128) = A(128xK) * B(128xK)^T. 4 waves, each 64x64 as 2x2 of 32x32.
// A-frag: m = lane%32, k = (lane/32)*8 + i   (analog of verified 16x16x32 layout)
// C/D:    col = lane&31, row = (reg&3) + 8*(reg>>2) + 4*(lane>>5)   [m74/m101]
__device__ __forceinline__ void gemm_bt_main(const unsigned short* __restrict__ Ab,
                                             const unsigned short* __restrict__ Bb,
                                             int lda, int ldb, int K,
                                             unsigned short* As, unsigned short* Bs,
                                             floatx16 acc[2][2]) {
  const int t = threadIdx.x;
  const int l = t & 63;
  const int w = t >> 6;
  const int wm = w >> 1, wn = w & 1;
  const int sr = t >> 2;
  const int sc = (t & 3) << 3;
#pragma unroll
  for (int i = 0; i < 2; ++i)
#pragma unroll
    for (int j = 0; j < 2; ++j)
#pragma unroll
      for (int e = 0; e < 16; ++e) acc[i][j][e] = 0.f;

  const int ar = l & 31;              // row within 32-subtile
  const int khalf = (l >> 5) << 3;    // 0 or 8

  for (int k0 = 0; k0 < K; k0 += 32) {
    async16(Ab + (size_t)sr * lda + k0 + sc, As + t * 8);
    async16(Ab + (size_t)(sr + 64) * lda + k0 + sc, As + 2048 + t * 8);
    async16(Bb + (size_t)sr * ldb + k0 + sc, Bs + t * 8);
    async16(Bb + (size_t)(sr + 64) * ldb + k0 + sc, Bs + 2048 + t * 8);
    __syncthreads();
#pragma unroll
    for (int ks = 0; ks < 2; ++ks) {
      const int ko = ks * 16 + khalf;
      bf16x8 a0 = *(const bf16x8*)(const void*)(As + (wm * 64 + ar) * 32 + ko);
      bf16x8 a1 = *(const bf16x8*)(const void*)(As + (wm * 64 + 32 + ar) * 32 + ko);
      bf16x8 b0 = *(const bf16x8*)(const void*)(Bs + (wn * 64 + ar) * 32 + ko);
      bf16x8 b1 = *(const bf16x8*)(const void*)(Bs + (wn * 64 + 32 + ar) * 32 + ko);
      acc[0][0] = __builtin_amdgcn_mfma_f32_32x32x16_bf16(a0, b0, acc[0][0], 0, 0, 0);
      acc[0][1] = __builtin_amdgcn_mfma_f32_32x32x16_bf16(a0, b1, acc[0][1], 0, 0, 0);
      acc[1][0] = __builtin_amdgcn_mfma_f32_32x32x16_bf16(a1, b0, acc[1][0], 0, 0, 0);
      acc[1][1] = __builtin_amdgcn_mfma_f32_32x32x16_bf16(a1, b1, acc[1][1], 0, 0, 0);
    }
    __syncthreads();
  }
}

// ---- K0: fp32 -> bf16 conversion of X and the three W matrices ----
__global__ __launch_bounds__(256) void k_cvt(const float* __restrict__ X,
                                             const float* __restrict__ Wq,
                                             const float* __restrict__ Wk,
                                             const float* __restrict__ Wv,
                                             unsigned short* __restrict__ Xb,
                                             unsigned short* __restrict__ Wb) {
  const size_t NX = (size_t)Bn * Sn * Hn;
  const size_t NW = (size_t)Hn * Hn;
  size_t i = ((size_t)blockIdx.x * 256 + threadIdx.x) * 8;
  const float* src;
  unsigned short* dst;
  if (i < NX) {
    src = X + i;
    dst = Xb + i;
  } else {
    size_t j = i - NX;
    int wsel = (int)(j >> 20);
    size_t o = j & (NW - 1);
    src = (wsel == 0 ? Wq : wsel == 1 ? Wk : Wv) + o;
    dst = Wb + j;
  }
  floatx4 a = __builtin_nontemporal_load((const floatx4*)src);
  floatx4 b = __builtin_nontemporal_load((const floatx4*)(src + 4));
  ushort8v o8;
  o8[0] = f2bf(a[0]); o8[1] = f2bf(a[1]); o8[2] = f2bf(a[2]); o8[3] = f2bf(a[3]);
  o8[4] = f2bf(b[0]); o8[5] = f2bf(b[1]); o8[6] = f2bf(b[2]); o8[7] = f2bf(b[3]);
  *(ushort8v*)(void*)(dst) = o8;
}

// ---- K1: fused QKV projection GEMM ----
// blockIdx.x: 0..23 -> sel = x>>3 (0=Q,1=K,2=V), n0 = (x&7)*128; blockIdx.y: m-tile.
// sel 0 (Q): out scaled by 1/32 (exact pow2). sel 2 (V): transposed store Vt[b][h][s].
__global__ __launch_bounds__(256, 3) void k_projall(const unsigned short* __restrict__ Xb,
                                                    const unsigned short* __restrict__ Wb,
                                                    const float* __restrict__ bq,
                                                    const float* __restrict__ bk,
                                                    const float* __restrict__ bv,
                                                    unsigned short* __restrict__ Qb,
                                                    unsigned short* __restrict__ Kb,
                                                    unsigned short* __restrict__ Vt) {
  __shared__ unsigned short lds[16384];  // union: staging 2x4096 | transpose 128x128 swizzled
  unsigned short* As = lds;
  unsigned short* Bs = lds + 4096;
  const int sel = blockIdx.x >> 3;
  const int n0 = (blockIdx.x & 7) * 128;
  const int m0 = blockIdx.y * 128;
  const unsigned short* Ab = Xb + (size_t)m0 * Hn;
  const unsigned short* Bb = Wb + (size_t)sel * Hn * Hn + (size_t)n0 * Hn;
  floatx16 acc[2][2];
  gemm_bt_main(Ab, Bb, Hn, Hn, Hn, As, Bs, acc);

  const int t = threadIdx.x, l = t & 63, w = t >> 6;
  const int wm = w >> 1, wn = w & 1;
  const int cl = l & 31;
  const int rbase = (l >> 5) << 2;  // 0 or 4
  const float* bias = sel == 0 ? bq : sel == 1 ? bk : bv;
  const float oscale = sel == 0 ? 0.03125f : 1.0f;

  if (sel < 2) {
    unsigned short* Out = sel == 0 ? Qb : Kb;
#pragma unroll
    for (int nt = 0; nt < 2; ++nt) {
      const int col = n0 + wn * 64 + nt * 32 + cl;
      const float bb = bias[col];
#pragma unroll
      for (int mt = 0; mt < 2; ++mt) {
        const int rowb = m0 + wm * 64 + mt * 32 + rbase;
#pragma unroll
        for (int r = 0; r < 16; ++r) {
          const int row = rowb + (r & 3) + ((r >> 2) << 3);
          Out[(size_t)row * Hn + col] = f2bf((acc[mt][nt][r] + bb) * oscale);
        }
      }
    }
  } else {
    __syncthreads();  // staging LDS now reusable as transpose buffer
    // swizzled transpose layout: elt addr = nl*128 + ((ml>>3) ^ (nl&15))*8 + (ml&7)
#pragma unroll
    for (int nt = 0; nt < 2; ++nt) {
      const int nl = wn * 64 + nt * 32 + cl;
      const float bb = bias[n0 + nl];
#pragma unroll
      for (int mt = 0; mt < 2; ++mt) {
#pragma unroll
        for (int rg = 0; rg < 4; ++rg) {
          const int ml4 = wm * 64 + mt * 32 + rbase + rg * 8;  // 4 consecutive rows
          const int ga = ((ml4 >> 3) ^ (nl & 15)) * 8 + (ml4 & 7);
          ushort4 pk = make_ushort4(f2bf(acc[mt][nt][rg * 4 + 0] + bb),
                                    f2bf(acc[mt][nt][rg * 4 + 1] + bb),
                                    f2bf(acc[mt][nt][rg * 4 + 2] + bb),
                                    f2bf(acc[mt][nt][rg * 4 + 3] + bb));
          *(ushort4*)(void*)(lds + nl * 128 + ga) = pk;  // ds_write_b64
        }
      }
    }
    __syncthreads();
    const int bidx = m0 >> 11;
    const int mrow = m0 & (Sn - 1);
    unsigned short* Vp = Vt + (size_t)bidx * Hn * Sn + mrow;
#pragma unroll
    for (int j = 0; j < 8; ++j) {
      const int e = (j * 256 + t) * 8;
      const int nl = e >> 7, mlg = (e & 127) >> 3;
      bf16x8 v = *(const bf16x8*)(const void*)(lds + nl * 128 + (mlg ^ (nl & 15)) * 8);
      __builtin_nontemporal_store(v, (bf16x8*)(void*)(Vp + (size_t)(n0 + nl) * Sn + mlg * 8));
    }
  }
}

// ---- K2: Sc[b][q][k] = mask_k ? exp(Q'_b @ K_b^T) : 0  (Q pre-scaled by 1/32)
//      + fp32 row-sum partials atomically accumulated into Lsum[b][q].
__global__ __launch_bounds__(256, 3) void k_scores(const unsigned short* __restrict__ Q,
                                                   const unsigned short* __restrict__ Kmat,
                                                   const int* __restrict__ mask,
                                                   unsigned short* __restrict__ Sc,
                                                   float* __restrict__ Lsum) {
  __shared__ unsigned short As[128 * 32], Bs[128 * 32];
  const int b = blockIdx.z;
  const int n0 = blockIdx.x * 128, m0 = blockIdx.y * 128;
  const unsigned short* Ab = Q + (size_t)b * Sn * Hn + (size_t)m0 * Hn;
  const unsigned short* Bb = Kmat + (size_t)b * Sn * Hn + (size_t)n0 * Hn;
  floatx16 acc[2][2];
  gemm_bt_main(Ab, Bb, Hn, Hn, Hn, As, Bs, acc);

  const int t = threadIdx.x, l = t & 63, w = t >> 6;
  const int wm = w >> 1, wn = w & 1;
  const int cl = l & 31;
  const int rbase = (l >> 5) << 2;
  unsigned short* C = Sc + (size_t)b * Sn * Sn;
  const int* mrow = mask + b * Sn;
  float rs[2][16];
#pragma unroll
  for (int mt = 0; mt < 2; ++mt)
#pragma unroll
    for (int r = 0; r < 16; ++r) rs[mt][r] = 0.f;

#pragma unroll
  for (int nt = 0; nt < 2; ++nt) {
    const int col = n0 + wn * 64 + nt * 32 + cl;
    const int mk = mrow[col];
#pragma unroll
    for (int mt = 0; mt < 2; ++mt) {
      const int rowb = m0 + wm * 64 + mt * 32 + rbase;
#pragma unroll
      for (int r = 0; r < 16; ++r) {
        const int row = rowb + (r & 3) + ((r >> 2) << 3);
        const float e = mk != 0 ? __expf(acc[mt][nt][r]) : 0.f;  // |s|<~10, no max needed
        C[(size_t)row * Sn + col] = f2bf(e);
        rs[mt][r] += e;
      }
    }
  }
  // reduce row-sum partials across the 32 col-lanes of each half-wave
#pragma unroll
  for (int mt = 0; mt < 2; ++mt)
#pragma unroll
    for (int r = 0; r < 16; ++r) {
      float v = rs[mt][r];
      v += __shfl_xor(v, 1);
      v += __shfl_xor(v, 2);
      v += __shfl_xor(v, 4);
      v += __shfl_xor(v, 8);
      v += __shfl_xor(v, 16);
      rs[mt][r] = v;
    }
  if (cl == 0) {
#pragma unroll
    for (int mt = 0; mt < 2; ++mt) {
      const int rowb = m0 + wm * 64 + mt * 32 + rbase;
#pragma unroll
      for (int r = 0; r < 16; ++r)
        atomicAdd(&Lsum[b * Sn + rowb + (r & 3) + ((r >> 2) << 3)], rs[mt][r]);
    }
  }
}

// ---- K3: Out[b][q][h] = (Sc_b @ Vt_b^T) * (qmask ? 1/Lsum : 0), fp32 nt out ----
__global__ __launch_bounds__(256, 3) void k_out(const unsigned short* __restrict__ Wt,
                                                const unsigned short* __restrict__ Vt,
                                                const int* __restrict__ mask,
                                                const float* __restrict__ Lsum,
                                                float* __restrict__ Out) {
  __shared__ unsigned short As[128 * 32], Bs[128 * 32];
  const int b = blockIdx.z;
  const int n0 = blockIdx.x * 128, m0 = blockIdx.y * 128;
  const unsigned short* Ab = Wt + (size_t)b * Sn * Sn + (size_t)m0 * Sn;
  const unsigned short* Bb = Vt + (size_t)b * Hn * Sn + (size_t)n0 * Sn;
  floatx16 acc[2][2];
  gemm_bt_main(Ab, Bb, Sn, Sn, Sn, As, Bs, acc);

  const int t = threadIdx.x, l = t & 63, w = t >> 6;
  const int wm = w >> 1, wn = w & 1;
  const int cl = l & 31;
  const int rbase = (l >> 5) << 2;
  float* C = Out + (size_t)b * Sn * Hn;
  const int* mrow = mask + b * Sn;
#pragma unroll
  for (int mt = 0; mt < 2; ++mt) {
    const int rowb = m0 + wm * 64 + mt * 32 + rbase;
    float inv[16];
#pragma unroll
    for (int r = 0; r < 16; ++r) {
      const int row = rowb + (r & 3) + ((r >> 2) << 3);
      inv[r] = mrow[row] != 0 ? 1.0f / Lsum[b * Sn + row] : 0.f;
    }
#pragma unroll
    for (int nt = 0; nt < 2; ++nt) {
      const int col = n0 + wn * 64 + nt * 32 + cl;
#pragma unroll
      for (int r = 0; r < 16; ++r) {
        const int row = rowb + (r & 3) + ((r >> 2) << 3);
        __builtin_nontemporal_store(acc[mt][nt][r] * inv[r], &C[(size_t)row * Hn + col]);
      }
    }
  }
}

extern "C" void kernel_launch(void* const* d_in, const int* in_sizes, int n_in,
                              void* d_out, int out_size, void* d_ws, size_t ws_size,
                              hipStream_t stream) {
  const float* X = (const float*)d_in[0];
  const int* mask = (const int*)d_in[1];
  const float* Wq = (const float*)d_in[2];
  const float* bq = (const float*)d_in[3];
  const float* Wk = (const float*)d_in[4];
  const float* bk = (const float*)d_in[5];
  const float* Wv = (const float*)d_in[6];
  const float* bv = (const float*)d_in[7];
  float* Out = (float*)d_out;

  const size_t NE = (size_t)Bn * Sn * Hn;      // 33,554,432
  const size_t NW = (size_t)Hn * Hn;
  unsigned short* Qb = (unsigned short*)d_ws;  // 64 MiB
  unsigned short* Kb = Qb + NE;                // 64 MiB
  unsigned short* Vt = Kb + NE;                // 64 MiB, layout [b][h][s]
  unsigned short* Sc = Vt + NE;                // 128 MiB, layout [b][q][k]
  unsigned short* Xb = Sc + (size_t)Bn * Sn * Sn;  // 64 MiB
  unsigned short* Wb = Xb + NE;                // 6 MiB, [3][Hn][Hn]
  float* Lsum = (float*)Wb;                    // 128 KiB, aliases Wb (dead after projall)

  dim3 blk(256, 1, 1);
  const int cvt_blocks = (int)((NE + 3 * NW) / 8 / 256);
  k_cvt<<<dim3(cvt_blocks, 1, 1), blk, 0, stream>>>(X, Wq, Wk, Wv, Xb, Wb);
  k_projall<<<dim3(24, (Bn * Sn) / 128, 1), blk, 0, stream>>>(Xb, Wb, bq, bk, bv, Qb, Kb, Vt);
  hipMemsetAsync(Lsum, 0, (size_t)Bn * Sn * sizeof(float), stream);
  k_scores<<<dim3(Sn / 128, Sn / 128, Bn), blk, 0, stream>>>(Qb, Kb, mask, Sc, Lsum);
  k_out<<<dim3(Hn / 128, Sn / 128, Bn), blk, 0, stream>>>(Sc, Vt, mask, Lsum, Out);
}